// Round 6
// baseline (332.811 us; speedup 1.0000x reference)
//
#include <hip/hip_runtime.h>
#include <stdint.h>
#include <math.h>

typedef unsigned short u16;
typedef __attribute__((ext_vector_type(8))) short short8;
typedef __attribute__((ext_vector_type(4))) float floatx4;
typedef __attribute__((ext_vector_type(4))) unsigned short ushort4v;

#define MFMA16(a, b, c) __builtin_amdgcn_mfma_f32_16x16x32_bf16(a, b, c, 0, 0, 0)

// ---- problem constants ----
constexpr int B_ = 4, N_ = 2048, C_ = 1024, H_ = 16, HD = 64;
constexpr size_t SZ_X = (size_t)B_ * N_ * C_;       // 8388608
constexpr size_t SZ_WQKV = (size_t)3 * C_ * C_;     // 3145728
constexpr size_t SZ_WPROJ = (size_t)C_ * C_;        // 1048576
constexpr size_t SZ_QKV = (size_t)B_ * H_ * N_ * HD; // 8388608 per tensor

// softmax scale (1/sqrt(64)) * log2(e), folded into q so scores are exp2-ready
#define QSCALE 0.1803368801111204f

__device__ __forceinline__ u16 f2bf(float f) {
  union { float f; uint32_t u; } c; c.f = f;
  uint32_t u = c.u;
  return (u16)((u + 0x7FFFu + ((u >> 16) & 1u)) >> 16);  // RNE
}
// Schraudolph: bf16 bit pattern of 2^s in one fma + one cvt (s in [-30, +30])
// bits = (int)(s*128 + (127*128 - 5.59 + 0.5)) ; max rel err ~2.9%, zero-mean
__device__ __forceinline__ uint32_t p2b(float s) {
  return (uint32_t)(int)__builtin_fmaf(s, 128.0f, 16250.91f);
}
// async global->LDS, 16B per lane; LDS dest = wave-uniform base + lane*16
__device__ __forceinline__ void async16(const u16* g, u16* l) {
  __builtin_amdgcn_global_load_lds(
      (const __attribute__((address_space(1))) void*)g,
      (__attribute__((address_space(3))) void*)l, 16, 0, 0);
}

// ---------------- fp32 -> bf16 cast ----------------
__global__ __launch_bounds__(256) void cvt_bf16(const float* __restrict__ in,
                                                u16* __restrict__ out, int n4) {
  int i = blockIdx.x * 256 + threadIdx.x;
  if (i >= n4) return;
  float4 v = ((const float4*)in)[i];
  ushort4v o;
  o.x = f2bf(v.x); o.y = f2bf(v.y); o.z = f2bf(v.z); o.w = f2bf(v.w);
  ((ushort4v*)out)[i] = o;
}

// ---------------- GEMM: C[m,n] = sum_k A[m,k]*B[n,k] ----------------
// 128x128 tile, BK=32, 4 waves (each 64x64), 16x16x32 bf16 MFMA.
// DOUBLE-BUFFERED staging: one barrier per K-iter; DMA for tile k+1 issued
// right after the barrier, drained by the compiler's vmcnt(0) at the NEXT
// barrier (a full compute phase later) -> no per-iter drain stall.
// MODE 0: fused RMSNorm+RoPE epilogue -> qb/kb [b,h,n,e] (q pre-scaled by
//         QSCALE), vtb [b,h,e,n] (bf16). Wave's 64-col block = one (t,head).
// MODE 1: outf[m*N+n] = acc + bias[n] (fp32)
template <int MODE>
__global__ __launch_bounds__(256) void gemm_bt(
    const u16* __restrict__ A, const u16* __restrict__ Bm, int K,
    u16* __restrict__ qb, u16* __restrict__ kb, u16* __restrict__ vtb,
    float* __restrict__ outf, const float* __restrict__ bias, int N,
    const float* __restrict__ cosp, const float* __restrict__ sinp,
    const float* __restrict__ qw, const float* __restrict__ kw) {
  const int tid = threadIdx.x;
  const int wave = tid >> 6;
  const int lane = tid & 63;
  const int quad = lane >> 4;
  const int l16 = lane & 15;
  const int bm0 = blockIdx.x * 128;
  const int bn0 = blockIdx.y * 128;
  const int wm = (wave >> 1) * 64;
  const int wn = (wave & 1) * 64;

  __shared__ __align__(16) u16 As[2][128 * 32];
  __shared__ __align__(16) u16 Bs[2][128 * 32];

  floatx4 acc[4][4];
#pragma unroll
  for (int i = 0; i < 4; ++i)
#pragma unroll
    for (int j = 0; j < 4; ++j)
#pragma unroll
      for (int r = 0; r < 4; ++r) acc[i][j][r] = 0.f;

  auto stage = [&](int k0, int buf) {
#pragma unroll
    for (int j = 0; j < 2; ++j) {
      const int seg = tid + j * 256;       // 512 segs of 16B per tile
      const int row = seg >> 2;
      const int ks = (seg & 3) * 8;
      u16* la = As[buf] + (size_t)(wave * 64 + j * 256) * 8;  // wave-uniform
      u16* lb = Bs[buf] + (size_t)(wave * 64 + j * 256) * 8;
      async16(A + (size_t)(bm0 + row) * K + k0 + ks, la);
      async16(Bm + (size_t)(bn0 + row) * K + k0 + ks, lb);
    }
  };

  const int niter = K >> 5;
  stage(0, 0);
  for (int kt = 0; kt < niter; ++kt) {
    __syncthreads();  // drains DMA(kt) [vmcnt(0) before s_barrier] + WAR guard
    if (kt + 1 < niter) stage((kt + 1) << 5, (kt + 1) & 1);
    const u16* as = As[kt & 1];
    const u16* bs = Bs[kt & 1];

    short8 af[4], bf[4];
#pragma unroll
    for (int t = 0; t < 4; ++t)
      af[t] = *(const short8*)(as + (wm + t * 16 + l16) * 32 + quad * 8);
#pragma unroll
    for (int t = 0; t < 4; ++t)
      bf[t] = *(const short8*)(bs + (wn + t * 16 + l16) * 32 + quad * 8);
#pragma unroll
    for (int i = 0; i < 4; ++i)
#pragma unroll
      for (int j = 0; j < 4; ++j)
        acc[i][j] = MFMA16(af[i], bf[j], acc[i][j]);
  }

  // C/D layout: row = quad*4 + r, col = l16 (per 16x16 tile)
  if (MODE == 0) {
    const int hb = (bn0 + wn) >> 6;  // head-block 0..47, wave-uniform
    const int t = hb >> 4;           // 0=q, 1=k, 2=v
    const int h = hb & 15;
    if (t < 2) {
      const float* w = (t == 0) ? qw : kw;
      u16* dstb = (t == 0) ? qb : kb;
      float wv[4];
#pragma unroll
      for (int j = 0; j < 4; ++j) wv[j] = w[j * 16 + l16];
#pragma unroll
      for (int i = 0; i < 4; ++i)
#pragma unroll
        for (int r = 0; r < 4; ++r) {
          const int m = bm0 + wm + i * 16 + quad * 4 + r;
          const int b = m >> 11, tok = m & 2047;
          float ss = 0.f;
#pragma unroll
          for (int j = 0; j < 4; ++j) ss += acc[i][j][r] * acc[i][j][r];
          ss += __shfl_xor(ss, 1);
          ss += __shfl_xor(ss, 2);
          ss += __shfl_xor(ss, 4);
          ss += __shfl_xor(ss, 8);
          const float inv = 1.0f / sqrtf(ss * (1.0f / 64.0f) + 1e-6f);
          float xn[4];
#pragma unroll
          for (int j = 0; j < 4; ++j) xn[j] = acc[i][j][r] * inv * wv[j];
          u16* dst = dstb + ((size_t)(b * 16 + h) * 2048 + tok) * 64;
#pragma unroll
          for (int j = 0; j < 4; ++j) {
            const int e = j * 16 + l16;
            const float cs = cosp[tok * 64 + e];
            const float sn = sinp[tok * 64 + e];
            const float rot = (j < 2) ? -xn[j + 2] : xn[j - 2];
            float o = xn[j] * cs + rot * sn;
            if (t == 0) o *= QSCALE;
            dst[e] = f2bf(o);
          }
        }
    } else {  // v: store transposed [b,h,e,n]
#pragma unroll
      for (int i = 0; i < 4; ++i)
#pragma unroll
        for (int j = 0; j < 4; ++j)
#pragma unroll
          for (int r = 0; r < 4; ++r) {
            const int m = bm0 + wm + i * 16 + quad * 4 + r;
            const int b = m >> 11, tok = m & 2047;
            const int e = j * 16 + l16;
            vtb[((size_t)(b * 16 + h) * 64 + e) * 2048 + tok] =
                f2bf(acc[i][j][r]);
          }
    }
  } else {
#pragma unroll
    for (int i = 0; i < 4; ++i)
#pragma unroll
      for (int j = 0; j < 4; ++j)
#pragma unroll
        for (int r = 0; r < 4; ++r) {
          const int m = bm0 + wm + i * 16 + quad * 4 + r;
          const int n = bn0 + wn + j * 16 + l16;
          outf[(size_t)m * N + n] = acc[i][j][r] + bias[n];
        }
  }
}

// ---------------- Flash attention: 256-row Q tile, dbuf staging ----------
// 64 q-rows per wave (4 subs): K/V fragments read from LDS ONCE per iter
// into registers and reused across all 4 subs -> LDS-pipe bytes per q-row
// halved vs 2-sub version (LDS pipe was the r5 bottleneck).
// Single-barrier double-buffered K/V staging (global_load_lds, fragment
// order). Operand-swapped S^T = K*Q^T; P goes through per-wave LDS
// (b64 writes / b128 reads, lgkmcnt-only ordering; buffers alternate
// sub&1 -- the per-sub lgkmcnt(0) also drains the previous same-buffer
// sub's reads). Schraudolph exp2->bf16 (fma+cvt, no v_exp). Fixed-max
// softmax (scores bounded); l via all-ones MFMA. XCD-aware bh swizzle.
__global__ __launch_bounds__(256) void attn_kernel(
    const u16* __restrict__ qb, const u16* __restrict__ kb,
    const u16* __restrict__ vtb, u16* __restrict__ ob) {
  const int tid = threadIdx.x;
  const int wave = tid >> 6, lane = tid & 63;
  const int quad = lane >> 4, l16 = lane & 15;

  // XCD swizzle: all 8 q-blocks of a bh land on one XCD (linear id % 8)
  const int id = blockIdx.x + blockIdx.y * 8;  // grid (8,64)
  const int xcd = id & 7;
  const int grp = id >> 3;                     // 0..63
  const int bh = xcd * 8 + (grp & 7);
  const int q0 = (grp >> 3) * 256;

  __shared__ __align__(16) u16 Ksf[2][64 * 64];    // 16 KB
  __shared__ __align__(16) u16 Vsf[2][64 * 64];    // 16 KB
  __shared__ __align__(16) u16 Ps[4][2][16 * 72];  // 18 KB

  const u16* qptr = qb + (size_t)bh * (2048 * 64);
  const u16* kptr = kb + (size_t)bh * (2048 * 64);
  const u16* vptr = vtb + (size_t)bh * (64 * 2048);

  // staging addresses: seg = ct*128 + hf*64 + lane, fragment order
  const int s0 = tid, s1 = tid + 256;
  const int ct0 = s0 >> 7, ct1 = s1 >> 7;
  const int hf0 = (s0 >> 6) & 1, hf1 = (s1 >> 6) & 1;
  const u16* kg0 = kptr + (size_t)(ct0 * 16 + l16) * 64 + hf0 * 32 + quad * 8;
  const u16* kg1 = kptr + (size_t)(ct1 * 16 + l16) * 64 + hf1 * 32 + quad * 8;
  const u16* vg0 = vptr + (size_t)(ct0 * 16 + l16) * 2048 + hf0 * 32 + quad * 8;
  const u16* vg1 = vptr + (size_t)(ct1 * 16 + l16) * 2048 + hf1 * 32 + quad * 8;
  const int lo0 = (wave * 64) * 8;          // wave-uniform LDS bases
  const int lo1 = (256 + wave * 64) * 8;

  // Q B-frags: 4 q-subtiles of 16 rows (B[k=e][n=q]: n=l16, k=quad*8+j)
  short8 aq[4][2];
#pragma unroll
  for (int sub = 0; sub < 4; ++sub) {
    const int qrow = q0 + wave * 64 + sub * 16 + l16;
#pragma unroll
    for (int hf = 0; hf < 2; ++hf)
      aq[sub][hf] =
          *(const short8*)(qptr + (size_t)qrow * 64 + hf * 32 + quad * 8);
  }

  // all-ones bf16 B fragment for the l = P*1 row-sum MFMA
  short8 ones;
#pragma unroll
  for (int j = 0; j < 8; ++j) ones[j] = (short)0x3F80;

  floatx4 o[4][4], ol[4];
#pragma unroll
  for (int sub = 0; sub < 4; ++sub) {
#pragma unroll
    for (int r = 0; r < 4; ++r) ol[sub][r] = 0.f;
#pragma unroll
    for (int et = 0; et < 4; ++et)
#pragma unroll
      for (int r = 0; r < 4; ++r) o[sub][et][r] = 0.f;
  }

  // prologue stage of tile 0
  async16(kg0, Ksf[0] + lo0);
  async16(kg1, Ksf[0] + lo1);
  async16(vg0, Vsf[0] + lo0);
  async16(vg1, Vsf[0] + lo1);

  for (int it = 0; it < 32; ++it) {
    __syncthreads();  // drains DMA(it); WAR-guards buffer (it+1)&1
    if (it + 1 < 32) {
      const int n1 = (it + 1) * 64;
      const int b1 = (it + 1) & 1;
      async16(kg0 + (size_t)n1 * 64, Ksf[b1] + lo0);
      async16(kg1 + (size_t)n1 * 64, Ksf[b1] + lo1);
      async16(vg0 + n1, Vsf[b1] + lo0);
      async16(vg1 + n1, Vsf[b1] + lo1);
    }
    const u16* Kt = Ksf[it & 1];
    const u16* Vt = Vsf[it & 1];

    // K and V fragments once per iter, reused by all 4 subs
    short8 kf[4][2], vf[4][2];
#pragma unroll
    for (int t = 0; t < 4; ++t) {
      kf[t][0] = *(const short8*)(Kt + t * 1024 + lane * 8);
      kf[t][1] = *(const short8*)(Kt + t * 1024 + 512 + lane * 8);
    }
#pragma unroll
    for (int et = 0; et < 4; ++et) {
      vf[et][0] = *(const short8*)(Vt + et * 1024 + lane * 8);
      vf[et][1] = *(const short8*)(Vt + et * 1024 + 512 + lane * 8);
    }

#pragma unroll
    for (int sub = 0; sub < 4; ++sub) {
      u16* pb = Ps[wave][sub & 1];
      // S^T = K . Q^T ; Schraudolph 2^s -> bf16 bits; b64-write P[q][key]
#pragma unroll
      for (int t = 0; t < 4; ++t) {
        floatx4 z;
#pragma unroll
        for (int r = 0; r < 4; ++r) z[r] = 0.f;
        z = MFMA16(kf[t][0], aq[sub][0], z);
        z = MFMA16(kf[t][1], aq[sub][1], z);
        // D[key = t*16+quad*4+r][q = l16]
        uint2 w;
        w.x = p2b(z[0]) | (p2b(z[1]) << 16);
        w.y = p2b(z[2]) | (p2b(z[3]) << 16);
        *(uint2*)(pb + l16 * 72 + t * 16 + quad * 4) = w;
      }
      // drain P writes (also drains the sub-2 reads of this buffer)
      __asm__ volatile("s_waitcnt lgkmcnt(0)" ::: "memory");
      const short8 pa0 = *(const short8*)(pb + l16 * 72 + quad * 8);
      const short8 pa1 = *(const short8*)(pb + l16 * 72 + 32 + quad * 8);
      // O += P . V ; l += P . 1
#pragma unroll
      for (int et = 0; et < 4; ++et) {
        o[sub][et] = MFMA16(pa0, vf[et][0], o[sub][et]);
        o[sub][et] = MFMA16(pa1, vf[et][1], o[sub][et]);
      }
      ol[sub] = MFMA16(pa0, ones, ol[sub]);
      ol[sub] = MFMA16(pa1, ones, ol[sub]);
    }
  }

  // epilogue: O / l -> ob[b][n][h*64+e] (bf16)
  const int b = bh >> 4, h = bh & 15;
#pragma unroll
  for (int sub = 0; sub < 4; ++sub) {
    float inv[4];
#pragma unroll
    for (int r = 0; r < 4; ++r) inv[r] = 1.0f / ol[sub][r];
#pragma unroll
    for (int et = 0; et < 4; ++et)
#pragma unroll
      for (int r = 0; r < 4; ++r) {
        const int row = q0 + wave * 64 + sub * 16 + quad * 4 + r;
        const int e = et * 16 + l16;
        ob[((size_t)b * 2048 + row) * 1024 + h * 64 + e] =
            f2bf(o[sub][et][r] * inv[r]);
      }
  }
}

extern "C" void kernel_launch(void* const* d_in, const int* in_sizes, int n_in,
                              void* d_out, int out_size, void* d_ws, size_t ws_size,
                              hipStream_t stream) {
  const float* x     = (const float*)d_in[0];
  const float* cosp  = (const float*)d_in[1];
  const float* sinp  = (const float*)d_in[2];
  const float* wqkv  = (const float*)d_in[3];
  const float* wproj = (const float*)d_in[4];
  const float* bias  = (const float*)d_in[5];
  const float* qw    = (const float*)d_in[6];
  const float* kw    = (const float*)d_in[7];
  float* out = (float*)d_out;

  // workspace layout (u16), total ~88 MB
  u16* xb     = (u16*)d_ws;
  u16* wqkvb  = xb + SZ_X;
  u16* wprojb = wqkvb + SZ_WQKV;
  u16* qb     = wprojb + SZ_WPROJ;
  u16* kb     = qb + SZ_QKV;
  u16* vtb    = kb + SZ_QKV;
  u16* ob     = vtb + SZ_QKV;

  cvt_bf16<<<(int)(SZ_X / 4 / 256), 256, 0, stream>>>(x, xb, (int)(SZ_X / 4));
  cvt_bf16<<<(int)(SZ_WQKV / 4 / 256), 256, 0, stream>>>(wqkv, wqkvb, (int)(SZ_WQKV / 4));
  cvt_bf16<<<(int)(SZ_WPROJ / 4 / 256), 256, 0, stream>>>(wproj, wprojb, (int)(SZ_WPROJ / 4));

  gemm_bt<0><<<dim3(64, 24), 256, 0, stream>>>(xb, wqkvb, 1024, qb, kb, vtb,
                                               nullptr, nullptr, 3072,
                                               cosp, sinp, qw, kw);
  attn_kernel<<<dim3(8, 64), 256, 0, stream>>>(qb, kb, vtb, ob);
  gemm_bt<1><<<dim3(64, 8), 256, 0, stream>>>(ob, wprojb, 1024, nullptr, nullptr,
                                              nullptr, out, bias, 1024,
                                              nullptr, nullptr, nullptr, nullptr);
}

// Round 7
// 304.981 us; speedup vs baseline: 1.0913x; 1.0913x over previous
//
#include <hip/hip_runtime.h>
#include <stdint.h>
#include <math.h>

typedef unsigned short u16;
typedef __attribute__((ext_vector_type(8))) short short8;
typedef __attribute__((ext_vector_type(4))) float floatx4;
typedef __attribute__((ext_vector_type(4))) unsigned short ushort4v;

#define MFMA16(a, b, c) __builtin_amdgcn_mfma_f32_16x16x32_bf16(a, b, c, 0, 0, 0)

// ---- problem constants ----
constexpr int B_ = 4, N_ = 2048, C_ = 1024, H_ = 16, HD = 64;
constexpr size_t SZ_X = (size_t)B_ * N_ * C_;       // 8388608
constexpr size_t SZ_WQKV = (size_t)3 * C_ * C_;     // 3145728
constexpr size_t SZ_WPROJ = (size_t)C_ * C_;        // 1048576
constexpr size_t SZ_QKV = (size_t)B_ * H_ * N_ * HD; // 8388608 per tensor

// softmax scale (1/sqrt(64)) * log2(e), folded into q so scores are exp2-ready
#define QSCALE 0.1803368801111204f

__device__ __forceinline__ u16 f2bf(float f) {
  union { float f; uint32_t u; } c; c.f = f;
  uint32_t u = c.u;
  return (u16)((u + 0x7FFFu + ((u >> 16) & 1u)) >> 16);  // RNE
}
// Schraudolph: bf16 bit pattern of 2^s in one fma + one cvt (s in [-30, +30])
// bits = (int)(s*128 + (127*128 - 5.59 + 0.5)) ; max rel err ~2.9%, zero-mean;
// common mode cancels in p/sum(p). Validated r6: absmax 2.9e-3 < 3.9e-3.
__device__ __forceinline__ uint32_t p2b(float s) {
  return (uint32_t)(int)__builtin_fmaf(s, 128.0f, 16250.91f);
}
// async global->LDS, 16B per lane; LDS dest = wave-uniform base + lane*16
__device__ __forceinline__ void async16(const u16* g, u16* l) {
  __builtin_amdgcn_global_load_lds(
      (const __attribute__((address_space(1))) void*)g,
      (__attribute__((address_space(3))) void*)l, 16, 0, 0);
}

// ---------------- fp32 -> bf16 cast ----------------
__global__ __launch_bounds__(256) void cvt_bf16(const float* __restrict__ in,
                                                u16* __restrict__ out, int n4) {
  int i = blockIdx.x * 256 + threadIdx.x;
  if (i >= n4) return;
  float4 v = ((const float4*)in)[i];
  ushort4v o;
  o.x = f2bf(v.x); o.y = f2bf(v.y); o.z = f2bf(v.z); o.w = f2bf(v.w);
  ((ushort4v*)out)[i] = o;
}

// ---------------- GEMM: C[m,n] = sum_k A[m,k]*B[n,k] ----------------
// 128x128 tile, BK=32, 4 waves (each 64x64), 16x16x32 bf16 MFMA.
// Single-barrier double-buffered staging (DMA k+1 issued post-barrier,
// drained at the NEXT barrier after a full compute phase).
// XCD-banded swizzle: block linear id % 8 = XCD (dispatch round-robin);
// each XCD owns an 8-tile bm band (2 MB of A -> fits 4 MB per-XCD L2) and
// iterates all bn within it, so A re-reads across bn are L2 hits instead
// of L3 traffic. Requires gridDim.x == 64.
// MODE 0: fused RMSNorm+RoPE epilogue -> qb/kb [b,h,n,e] (q pre-scaled by
//         QSCALE), vtb [b,h,e,n] (bf16). Wave's 64-col block = one (t,head).
// MODE 1: outf[m*N+n] = acc + bias[n] (fp32)
template <int MODE>
__global__ __launch_bounds__(256) void gemm_bt(
    const u16* __restrict__ A, const u16* __restrict__ Bm, int K,
    u16* __restrict__ qb, u16* __restrict__ kb, u16* __restrict__ vtb,
    float* __restrict__ outf, const float* __restrict__ bias, int N,
    const float* __restrict__ cosp, const float* __restrict__ sinp,
    const float* __restrict__ qw, const float* __restrict__ kw) {
  const int tid = threadIdx.x;
  const int wave = tid >> 6;
  const int lane = tid & 63;
  const int quad = lane >> 4;
  const int l16 = lane & 15;
  // XCD-banded swizzle (gridDim.x == 64 -> 64 bm-tiles):
  const int id = blockIdx.x + blockIdx.y * 64;
  const int bm0 = ((id & 7) * 8 + ((id >> 3) & 7)) * 128;  // XCD band + local
  const int bn0 = (id >> 6) * 128;
  const int wm = (wave >> 1) * 64;
  const int wn = (wave & 1) * 64;

  __shared__ __align__(16) u16 As[2][128 * 32];
  __shared__ __align__(16) u16 Bs[2][128 * 32];

  floatx4 acc[4][4];
#pragma unroll
  for (int i = 0; i < 4; ++i)
#pragma unroll
    for (int j = 0; j < 4; ++j)
#pragma unroll
      for (int r = 0; r < 4; ++r) acc[i][j][r] = 0.f;

  auto stage = [&](int k0, int buf) {
#pragma unroll
    for (int j = 0; j < 2; ++j) {
      const int seg = tid + j * 256;       // 512 segs of 16B per tile
      const int row = seg >> 2;
      const int ks = (seg & 3) * 8;
      u16* la = As[buf] + (size_t)(wave * 64 + j * 256) * 8;  // wave-uniform
      u16* lb = Bs[buf] + (size_t)(wave * 64 + j * 256) * 8;
      async16(A + (size_t)(bm0 + row) * K + k0 + ks, la);
      async16(Bm + (size_t)(bn0 + row) * K + k0 + ks, lb);
    }
  };

  const int niter = K >> 5;
  stage(0, 0);
  for (int kt = 0; kt < niter; ++kt) {
    __syncthreads();  // drains DMA(kt) [vmcnt(0) before s_barrier] + WAR guard
    if (kt + 1 < niter) stage((kt + 1) << 5, (kt + 1) & 1);
    const u16* as = As[kt & 1];
    const u16* bs = Bs[kt & 1];

    short8 af[4], bf[4];
#pragma unroll
    for (int t = 0; t < 4; ++t)
      af[t] = *(const short8*)(as + (wm + t * 16 + l16) * 32 + quad * 8);
#pragma unroll
    for (int t = 0; t < 4; ++t)
      bf[t] = *(const short8*)(bs + (wn + t * 16 + l16) * 32 + quad * 8);
#pragma unroll
    for (int i = 0; i < 4; ++i)
#pragma unroll
      for (int j = 0; j < 4; ++j)
        acc[i][j] = MFMA16(af[i], bf[j], acc[i][j]);
  }

  // C/D layout: row = quad*4 + r, col = l16 (per 16x16 tile)
  if (MODE == 0) {
    const int hb = (bn0 + wn) >> 6;  // head-block 0..47, wave-uniform
    const int t = hb >> 4;           // 0=q, 1=k, 2=v
    const int h = hb & 15;
    if (t < 2) {
      const float* w = (t == 0) ? qw : kw;
      u16* dstb = (t == 0) ? qb : kb;
      float wv[4];
#pragma unroll
      for (int j = 0; j < 4; ++j) wv[j] = w[j * 16 + l16];
#pragma unroll
      for (int i = 0; i < 4; ++i)
#pragma unroll
        for (int r = 0; r < 4; ++r) {
          const int m = bm0 + wm + i * 16 + quad * 4 + r;
          const int b = m >> 11, tok = m & 2047;
          float ss = 0.f;
#pragma unroll
          for (int j = 0; j < 4; ++j) ss += acc[i][j][r] * acc[i][j][r];
          ss += __shfl_xor(ss, 1);
          ss += __shfl_xor(ss, 2);
          ss += __shfl_xor(ss, 4);
          ss += __shfl_xor(ss, 8);
          const float inv = 1.0f / sqrtf(ss * (1.0f / 64.0f) + 1e-6f);
          float xn[4];
#pragma unroll
          for (int j = 0; j < 4; ++j) xn[j] = acc[i][j][r] * inv * wv[j];
          u16* dst = dstb + ((size_t)(b * 16 + h) * 2048 + tok) * 64;
#pragma unroll
          for (int j = 0; j < 4; ++j) {
            const int e = j * 16 + l16;
            const float cs = cosp[tok * 64 + e];
            const float sn = sinp[tok * 64 + e];
            const float rot = (j < 2) ? -xn[j + 2] : xn[j - 2];
            float o = xn[j] * cs + rot * sn;
            if (t == 0) o *= QSCALE;
            dst[e] = f2bf(o);
          }
        }
    } else {  // v: store transposed [b,h,e,n]
#pragma unroll
      for (int i = 0; i < 4; ++i)
#pragma unroll
        for (int j = 0; j < 4; ++j)
#pragma unroll
          for (int r = 0; r < 4; ++r) {
            const int m = bm0 + wm + i * 16 + quad * 4 + r;
            const int b = m >> 11, tok = m & 2047;
            const int e = j * 16 + l16;
            vtb[((size_t)(b * 16 + h) * 64 + e) * 2048 + tok] =
                f2bf(acc[i][j][r]);
          }
    }
  } else {
#pragma unroll
    for (int i = 0; i < 4; ++i)
#pragma unroll
      for (int j = 0; j < 4; ++j)
#pragma unroll
        for (int r = 0; r < 4; ++r) {
          const int m = bm0 + wm + i * 16 + quad * 4 + r;
          const int n = bn0 + wn + j * 16 + l16;
          outf[(size_t)m * N + n] = acc[i][j][r] + bias[n];
        }
  }
}

// ---------------- Flash attention: 128-row Q tile, dbuf staging ----------
// r5 structure (the measured-best config: 32 q/wave, VGPR ~80, grid 1024,
// ~8 resident waves/CU) + Schraudolph softmax (fma+cvt replaces v_exp+f2bf,
// cuts softmax VALU ~2.2x at zero register cost).
// K/V staged via global_load_lds in MFMA-fragment order (conflict-free b128
// reads), single-barrier double-buffered. Operand-swapped S^T = K*Q^T so P
// lands in LDS as P[q][key] via b64 writes (same-wave round-trip, lgkmcnt
// only). Fixed-max softmax (scores bounded); l via all-ones MFMA. XCD-aware
// bh swizzle (8 bh per XCD -> K/V L2-resident).
__global__ __launch_bounds__(256) void attn_kernel(
    const u16* __restrict__ qb, const u16* __restrict__ kb,
    const u16* __restrict__ vtb, u16* __restrict__ ob) {
  const int tid = threadIdx.x;
  const int wave = tid >> 6, lane = tid & 63;
  const int quad = lane >> 4, l16 = lane & 15;

  // XCD swizzle: all 16 q-blocks of a bh land on one XCD (linear id % 8)
  const int id = blockIdx.x + blockIdx.y * 16;  // grid (16,64)
  const int bh = (id & 7) + 8 * ((id >> 3) & 7);
  const int q0 = (id >> 6) * 128;

  __shared__ __align__(16) u16 Ksf[2][64 * 64];    // 16 KB
  __shared__ __align__(16) u16 Vsf[2][64 * 64];    // 16 KB
  __shared__ __align__(16) u16 Ps[4][2][16 * 72];  // 18 KB

  const u16* qptr = qb + (size_t)bh * (2048 * 64);
  const u16* kptr = kb + (size_t)bh * (2048 * 64);
  const u16* vptr = vtb + (size_t)bh * (64 * 2048);

  // staging addresses: seg = ct*128 + hf*64 + lane, fragment order
  const int s0 = tid, s1 = tid + 256;
  const int ct0 = s0 >> 7, ct1 = s1 >> 7;
  const int hf0 = (s0 >> 6) & 1, hf1 = (s1 >> 6) & 1;
  const u16* kg0 = kptr + (size_t)(ct0 * 16 + l16) * 64 + hf0 * 32 + quad * 8;
  const u16* kg1 = kptr + (size_t)(ct1 * 16 + l16) * 64 + hf1 * 32 + quad * 8;
  const u16* vg0 = vptr + (size_t)(ct0 * 16 + l16) * 2048 + hf0 * 32 + quad * 8;
  const u16* vg1 = vptr + (size_t)(ct1 * 16 + l16) * 2048 + hf1 * 32 + quad * 8;
  const int lo0 = (wave * 64) * 8;          // wave-uniform LDS bases
  const int lo1 = (256 + wave * 64) * 8;

  // Q B-frags: 2 q-subtiles of 16 rows (B[k=e][n=q]: n=l16, k=quad*8+j)
  short8 aq[2][2];
#pragma unroll
  for (int sub = 0; sub < 2; ++sub) {
    const int qrow = q0 + wave * 32 + sub * 16 + l16;
#pragma unroll
    for (int hf = 0; hf < 2; ++hf)
      aq[sub][hf] =
          *(const short8*)(qptr + (size_t)qrow * 64 + hf * 32 + quad * 8);
  }

  // all-ones bf16 B fragment for the l = P*1 row-sum MFMA
  short8 ones;
#pragma unroll
  for (int j = 0; j < 8; ++j) ones[j] = (short)0x3F80;

  floatx4 o[2][4], ol[2];
#pragma unroll
  for (int sub = 0; sub < 2; ++sub) {
#pragma unroll
    for (int r = 0; r < 4; ++r) ol[sub][r] = 0.f;
#pragma unroll
    for (int et = 0; et < 4; ++et)
#pragma unroll
      for (int r = 0; r < 4; ++r) o[sub][et][r] = 0.f;
  }

  // prologue stage of tile 0
  async16(kg0, Ksf[0] + lo0);
  async16(kg1, Ksf[0] + lo1);
  async16(vg0, Vsf[0] + lo0);
  async16(vg1, Vsf[0] + lo1);

  for (int it = 0; it < 32; ++it) {
    __syncthreads();  // drains DMA(it); WAR-guards buffer (it+1)&1
    if (it + 1 < 32) {
      const int n1 = (it + 1) * 64;
      const int b1 = (it + 1) & 1;
      async16(kg0 + (size_t)n1 * 64, Ksf[b1] + lo0);
      async16(kg1 + (size_t)n1 * 64, Ksf[b1] + lo1);
      async16(vg0 + n1, Vsf[b1] + lo0);
      async16(vg1 + n1, Vsf[b1] + lo1);
    }
    const u16* Kt = Ksf[it & 1];
    const u16* Vt = Vsf[it & 1];

    // S^T = K . Q^T per 16-key tile; Schraudolph 2^s; b64-write P[q][key]
#pragma unroll
    for (int t = 0; t < 4; ++t) {
      const short8 kf0 = *(const short8*)(Kt + t * 1024 + lane * 8);
      const short8 kf1 = *(const short8*)(Kt + t * 1024 + 512 + lane * 8);
#pragma unroll
      for (int sub = 0; sub < 2; ++sub) {
        floatx4 z;
#pragma unroll
        for (int r = 0; r < 4; ++r) z[r] = 0.f;
        z = MFMA16(kf0, aq[sub][0], z);
        z = MFMA16(kf1, aq[sub][1], z);
        // D[key = t*16+quad*4+r][q = l16]
        uint2 w;
        w.x = p2b(z[0]) | (p2b(z[1]) << 16);
        w.y = p2b(z[2]) | (p2b(z[3]) << 16);
        *(uint2*)(Ps[wave][sub] + l16 * 72 + t * 16 + quad * 4) = w;
      }
    }

    // same-wave DS ordering: drain P writes before fragment reads
    __asm__ volatile("s_waitcnt lgkmcnt(0)" ::: "memory");

    short8 pa[2][2];
#pragma unroll
    for (int sub = 0; sub < 2; ++sub) {
      pa[sub][0] = *(const short8*)(Ps[wave][sub] + l16 * 72 + quad * 8);
      pa[sub][1] = *(const short8*)(Ps[wave][sub] + l16 * 72 + 32 + quad * 8);
    }

    // O += P . V ; l += P . 1
#pragma unroll
    for (int et = 0; et < 4; ++et) {
      const short8 vb0 = *(const short8*)(Vt + et * 1024 + lane * 8);
      const short8 vb1 = *(const short8*)(Vt + et * 1024 + 512 + lane * 8);
#pragma unroll
      for (int sub = 0; sub < 2; ++sub) {
        o[sub][et] = MFMA16(pa[sub][0], vb0, o[sub][et]);
        o[sub][et] = MFMA16(pa[sub][1], vb1, o[sub][et]);
      }
    }
#pragma unroll
    for (int sub = 0; sub < 2; ++sub) {
      ol[sub] = MFMA16(pa[sub][0], ones, ol[sub]);
      ol[sub] = MFMA16(pa[sub][1], ones, ol[sub]);
    }
  }

  // epilogue: O / l -> ob[b][n][h*64+e] (bf16)
  const int b = bh >> 4, h = bh & 15;
#pragma unroll
  for (int sub = 0; sub < 2; ++sub) {
    float inv[4];
#pragma unroll
    for (int r = 0; r < 4; ++r) inv[r] = 1.0f / ol[sub][r];
#pragma unroll
    for (int et = 0; et < 4; ++et)
#pragma unroll
      for (int r = 0; r < 4; ++r) {
        const int row = q0 + wave * 32 + sub * 16 + quad * 4 + r;
        const int e = et * 16 + l16;
        ob[((size_t)b * 2048 + row) * 1024 + h * 64 + e] =
            f2bf(o[sub][et][r] * inv[r]);
      }
  }
}

extern "C" void kernel_launch(void* const* d_in, const int* in_sizes, int n_in,
                              void* d_out, int out_size, void* d_ws, size_t ws_size,
                              hipStream_t stream) {
  const float* x     = (const float*)d_in[0];
  const float* cosp  = (const float*)d_in[1];
  const float* sinp  = (const float*)d_in[2];
  const float* wqkv  = (const float*)d_in[3];
  const float* wproj = (const float*)d_in[4];
  const float* bias  = (const float*)d_in[5];
  const float* qw    = (const float*)d_in[6];
  const float* kw    = (const float*)d_in[7];
  float* out = (float*)d_out;

  // workspace layout (u16), total ~88 MB
  u16* xb     = (u16*)d_ws;
  u16* wqkvb  = xb + SZ_X;
  u16* wprojb = wqkvb + SZ_WQKV;
  u16* qb     = wprojb + SZ_WPROJ;
  u16* kb     = qb + SZ_QKV;
  u16* vtb    = kb + SZ_QKV;
  u16* ob     = vtb + SZ_QKV;

  cvt_bf16<<<(int)(SZ_X / 4 / 256), 256, 0, stream>>>(x, xb, (int)(SZ_X / 4));
  cvt_bf16<<<(int)(SZ_WQKV / 4 / 256), 256, 0, stream>>>(wqkv, wqkvb, (int)(SZ_WQKV / 4));
  cvt_bf16<<<(int)(SZ_WPROJ / 4 / 256), 256, 0, stream>>>(wproj, wprojb, (int)(SZ_WPROJ / 4));

  gemm_bt<0><<<dim3(64, 24), 256, 0, stream>>>(xb, wqkvb, 1024, qb, kb, vtb,
                                               nullptr, nullptr, 3072,
                                               cosp, sinp, qw, kw);
  attn_kernel<<<dim3(16, 64), 256, 0, stream>>>(qb, kb, vtb, ob);
  gemm_bt<1><<<dim3(64, 8), 256, 0, stream>>>(ob, wprojb, 1024, nullptr, nullptr,
                                              nullptr, out, bias, 1024,
                                              nullptr, nullptr, nullptr, nullptr);
}

// Round 8
// 296.827 us; speedup vs baseline: 1.1212x; 1.0275x over previous
//
#include <hip/hip_runtime.h>
#include <stdint.h>
#include <math.h>

typedef unsigned short u16;
typedef __attribute__((ext_vector_type(8))) short short8;
typedef __attribute__((ext_vector_type(4))) float floatx4;
typedef __attribute__((ext_vector_type(4))) unsigned short ushort4v;

#define MFMA16(a, b, c) __builtin_amdgcn_mfma_f32_16x16x32_bf16(a, b, c, 0, 0, 0)

// ---- problem constants ----
constexpr int B_ = 4, N_ = 2048, C_ = 1024, H_ = 16, HD = 64;
constexpr size_t SZ_X = (size_t)B_ * N_ * C_;       // 8388608
constexpr size_t SZ_WQKV = (size_t)3 * C_ * C_;     // 3145728
constexpr size_t SZ_WPROJ = (size_t)C_ * C_;        // 1048576
constexpr size_t SZ_QKV = (size_t)B_ * H_ * N_ * HD; // 8388608 per tensor

// softmax scale (1/sqrt(64)) * log2(e), folded into q so scores are exp2-ready
#define QSCALE 0.1803368801111204f

__device__ __forceinline__ u16 f2bf(float f) {
  union { float f; uint32_t u; } c; c.f = f;
  uint32_t u = c.u;
  return (u16)((u + 0x7FFFu + ((u >> 16) & 1u)) >> 16);  // RNE
}
// Schraudolph: bf16 bit pattern of 2^s in one fma + one cvt (s in [-30, +30])
// zero-mean ~2.9% rel err; common mode cancels in p/sum(p). Validated r6/r7.
__device__ __forceinline__ uint32_t p2b(float s) {
  return (uint32_t)(int)__builtin_fmaf(s, 128.0f, 16250.91f);
}
// async global->LDS, 16B per lane; LDS dest = wave-uniform base + lane*16
__device__ __forceinline__ void async16(const u16* g, u16* l) {
  __builtin_amdgcn_global_load_lds(
      (const __attribute__((address_space(1))) void*)g,
      (__attribute__((address_space(3))) void*)l, 16, 0, 0);
}

// ---------------- fp32 -> bf16 cast, all three tensors in one launch -------
__global__ __launch_bounds__(256) void cvt_all(
    const float* __restrict__ x, const float* __restrict__ wqkv,
    const float* __restrict__ wproj, u16* __restrict__ xb,
    u16* __restrict__ wqkvb, u16* __restrict__ wprojb) {
  const int n1 = (int)(SZ_X / 4), n2 = (int)(SZ_WQKV / 4);
  int i = blockIdx.x * 256 + threadIdx.x;
  const float* src;
  u16* dst;
  int k;
  if (i < n1) { src = x; dst = xb; k = i; }
  else if (i < n1 + n2) { src = wqkv; dst = wqkvb; k = i - n1; }
  else { src = wproj; dst = wprojb; k = i - n1 - n2; }
  float4 v = ((const float4*)src)[k];
  ushort4v o;
  o.x = f2bf(v.x); o.y = f2bf(v.y); o.z = f2bf(v.z); o.w = f2bf(v.w);
  ((ushort4v*)dst)[k] = o;
}

// ---------------- GEMM: C[m,n] = sum_k A[m,k]*B[n,k] ----------------
// 128x128 tile, BK=32, 4 waves (each 64x64), single-barrier dbuf staging,
// XCD-banded swizzle (r7-validated).
// MODE 0 epilogue: fused RMSNorm+RoPE; q -> row-major [b,h,n,e] (pre-scaled
//   by QSCALE); k and v -> MFMA-FRAGMENT-ORDER 64-key tiles (4096 u16 per
//   tile) so attn's K DMA is address-linear and V fragments are directly
//   loadable coalesced from global.
// MODE 1: outf[m*N+n] = acc + bias[n] (fp32)
template <int MODE>
__global__ __launch_bounds__(256) void gemm_bt(
    const u16* __restrict__ A, const u16* __restrict__ Bm, int K,
    u16* __restrict__ qb, u16* __restrict__ kb, u16* __restrict__ vtb,
    float* __restrict__ outf, const float* __restrict__ bias, int N,
    const float* __restrict__ cosp, const float* __restrict__ sinp,
    const float* __restrict__ qw, const float* __restrict__ kw) {
  const int tid = threadIdx.x;
  const int wave = tid >> 6;
  const int lane = tid & 63;
  const int quad = lane >> 4;
  const int l16 = lane & 15;
  // XCD-banded swizzle (gridDim.x == 64 -> 64 bm-tiles):
  const int id = blockIdx.x + blockIdx.y * 64;
  const int bm0 = ((id & 7) * 8 + ((id >> 3) & 7)) * 128;  // XCD band + local
  const int bn0 = (id >> 6) * 128;
  const int wm = (wave >> 1) * 64;
  const int wn = (wave & 1) * 64;

  __shared__ __align__(16) u16 As[2][128 * 32];
  __shared__ __align__(16) u16 Bs[2][128 * 32];

  floatx4 acc[4][4];
#pragma unroll
  for (int i = 0; i < 4; ++i)
#pragma unroll
    for (int j = 0; j < 4; ++j)
#pragma unroll
      for (int r = 0; r < 4; ++r) acc[i][j][r] = 0.f;

  auto stage = [&](int k0, int buf) {
#pragma unroll
    for (int j = 0; j < 2; ++j) {
      const int seg = tid + j * 256;       // 512 segs of 16B per tile
      const int row = seg >> 2;
      const int ks = (seg & 3) * 8;
      u16* la = As[buf] + (size_t)(wave * 64 + j * 256) * 8;  // wave-uniform
      u16* lb = Bs[buf] + (size_t)(wave * 64 + j * 256) * 8;
      async16(A + (size_t)(bm0 + row) * K + k0 + ks, la);
      async16(Bm + (size_t)(bn0 + row) * K + k0 + ks, lb);
    }
  };

  const int niter = K >> 5;
  stage(0, 0);
  for (int kt = 0; kt < niter; ++kt) {
    __syncthreads();  // drains DMA(kt) [vmcnt(0) before s_barrier] + WAR guard
    if (kt + 1 < niter) stage((kt + 1) << 5, (kt + 1) & 1);
    const u16* as = As[kt & 1];
    const u16* bs = Bs[kt & 1];

    short8 af[4], bf[4];
#pragma unroll
    for (int t = 0; t < 4; ++t)
      af[t] = *(const short8*)(as + (wm + t * 16 + l16) * 32 + quad * 8);
#pragma unroll
    for (int t = 0; t < 4; ++t)
      bf[t] = *(const short8*)(bs + (wn + t * 16 + l16) * 32 + quad * 8);
#pragma unroll
    for (int i = 0; i < 4; ++i)
#pragma unroll
      for (int j = 0; j < 4; ++j)
        acc[i][j] = MFMA16(af[i], bf[j], acc[i][j]);
  }

  // C/D layout: row = quad*4 + r, col = l16 (per 16x16 tile)
  if (MODE == 0) {
    const int hb = (bn0 + wn) >> 6;  // head-block 0..47, wave-uniform
    const int t = hb >> 4;           // 0=q, 1=k, 2=v
    const int h = hb & 15;
    if (t < 2) {
      const float* w = (t == 0) ? qw : kw;
      float wv[4];
#pragma unroll
      for (int j = 0; j < 4; ++j) wv[j] = w[j * 16 + l16];
#pragma unroll
      for (int i = 0; i < 4; ++i)
#pragma unroll
        for (int r = 0; r < 4; ++r) {
          const int m = bm0 + wm + i * 16 + quad * 4 + r;
          const int b = m >> 11, tok = m & 2047;
          float ss = 0.f;
#pragma unroll
          for (int j = 0; j < 4; ++j) ss += acc[i][j][r] * acc[i][j][r];
          ss += __shfl_xor(ss, 1);
          ss += __shfl_xor(ss, 2);
          ss += __shfl_xor(ss, 4);
          ss += __shfl_xor(ss, 8);
          const float inv = 1.0f / sqrtf(ss * (1.0f / 64.0f) + 1e-6f);
          float xn[4];
#pragma unroll
          for (int j = 0; j < 4; ++j) xn[j] = acc[i][j][r] * inv * wv[j];
          const size_t bh = (size_t)(b * 16 + h);
#pragma unroll
          for (int j = 0; j < 4; ++j) {
            const int e = j * 16 + l16;
            const float cs = cosp[tok * 64 + e];
            const float sn = sinp[tok * 64 + e];
            const float rot = (j < 2) ? -xn[j + 2] : xn[j - 2];
            float o = xn[j] * cs + rot * sn;
            if (t == 0) {
              qb[(bh * 2048 + tok) * 64 + e] = f2bf(o * QSCALE);
            } else {
              // K fragment-order: tile kt=tok>>6; frag t3=(tok>>4)&3,
              // hf=e>>5; slot lane = quad_f*16 + (tok&15); elem = e&7
              const int kt2 = tok >> 6, t3 = (tok >> 4) & 3;
              const int hf = j >> 1;
              const int qf = (j & 1) * 2 + (l16 >> 3);
              kb[bh * 131072 + (size_t)kt2 * 4096 + (t3 * 2 + hf) * 512 +
                 (qf * 16 + (tok & 15)) * 8 + (l16 & 7)] = f2bf(o);
            }
          }
        }
    } else {  // v: fragment-order per 64-key tile
#pragma unroll
      for (int i = 0; i < 4; ++i)
#pragma unroll
        for (int j = 0; j < 4; ++j)
#pragma unroll
          for (int r = 0; r < 4; ++r) {
            const int m = bm0 + wm + i * 16 + quad * 4 + r;
            const int b = m >> 11, tok = m & 2047;
            // V^T frag: e=j*16+l16 -> et=j; key=tok -> hf,quad_f,elem
            const int kt2 = tok >> 6, nn = tok & 63;
            const int hf = nn >> 5, qf = (nn & 31) >> 3, jf = nn & 7;
            vtb[(size_t)(b * 16 + h) * 131072 + (size_t)kt2 * 4096 +
                (j * 2 + hf) * 512 + (qf * 16 + l16) * 8 + jf] =
                f2bf(acc[i][j][r]);
          }
    }
  } else {
#pragma unroll
    for (int i = 0; i < 4; ++i)
#pragma unroll
      for (int j = 0; j < 4; ++j)
#pragma unroll
        for (int r = 0; r < 4; ++r) {
          const int m = bm0 + wm + i * 16 + quad * 4 + r;
          const int n = bn0 + wn + j * 16 + l16;
          outf[(size_t)m * N + n] = acc[i][j][r] + bias[n];
        }
  }
}

// ---------------- Flash attention: 128-row Q tile ----------------
// K: LDS dbuf staging via address-LINEAR global_load_lds (K stored in
//    fragment order -> coalesced 4-full-line DMA), single barrier/iter.
// V: NO LDS -- fragment-order global layout read directly as coalesced
//    global_load_dwordx4 per wave (8 KB tile L1-resident across 4 waves);
//    issued at iter start, consumed after the S+softmax+P phase.
// P: per-wave LDS round-trip (b64 write / b128 read, lgkmcnt only).
// Fixed-max Schraudolph softmax; l via all-ones MFMA; XCD bh swizzle.
// LDS 34 KB -> 4 blocks/CU; __launch_bounds__(256,4) caps VGPR at 128.
__global__ __launch_bounds__(256, 4) void attn_kernel(
    const u16* __restrict__ qb, const u16* __restrict__ kb,
    const u16* __restrict__ vtb, u16* __restrict__ ob) {
  const int tid = threadIdx.x;
  const int wave = tid >> 6, lane = tid & 63;
  const int quad = lane >> 4, l16 = lane & 15;

  // XCD swizzle: all 16 q-blocks of a bh land on one XCD (linear id % 8)
  const int id = blockIdx.x + blockIdx.y * 16;  // grid (16,64)
  const int bh = (id & 7) + 8 * ((id >> 3) & 7);
  const int q0 = (id >> 6) * 128;

  __shared__ __align__(16) u16 Ksf[2][64 * 64];    // 16 KB
  __shared__ __align__(16) u16 Ps[4][2][16 * 72];  // 18 KB

  const u16* qptr = qb + (size_t)bh * (2048 * 64);
  const u16* kptr = kb + (size_t)bh * 131072;   // fragment-order tiles
  const u16* vptr = vtb + (size_t)bh * 131072;  // fragment-order tiles

  const int s0 = tid, s1 = tid + 256;           // linear 16B segs
  const int lo0 = (wave * 64) * 8;              // wave-uniform LDS bases
  const int lo1 = (256 + wave * 64) * 8;

  // Q B-frags: 2 q-subtiles of 16 rows (B[k=e][n=q]: n=l16, k=quad*8+j)
  short8 aq[2][2];
#pragma unroll
  for (int sub = 0; sub < 2; ++sub) {
    const int qrow = q0 + wave * 32 + sub * 16 + l16;
#pragma unroll
    for (int hf = 0; hf < 2; ++hf)
      aq[sub][hf] =
          *(const short8*)(qptr + (size_t)qrow * 64 + hf * 32 + quad * 8);
  }

  // all-ones bf16 B fragment for the l = P*1 row-sum MFMA
  short8 ones;
#pragma unroll
  for (int j = 0; j < 8; ++j) ones[j] = (short)0x3F80;

  floatx4 o[2][4], ol[2];
#pragma unroll
  for (int sub = 0; sub < 2; ++sub) {
#pragma unroll
    for (int r = 0; r < 4; ++r) ol[sub][r] = 0.f;
#pragma unroll
    for (int et = 0; et < 4; ++et)
#pragma unroll
      for (int r = 0; r < 4; ++r) o[sub][et][r] = 0.f;
  }

  // prologue stage of K tile 0 (address-linear coalesced DMA)
  async16(kptr + (size_t)s0 * 8, Ksf[0] + lo0);
  async16(kptr + (size_t)s1 * 8, Ksf[0] + lo1);

  for (int it = 0; it < 32; ++it) {
    __syncthreads();  // drains K DMA(it); WAR-guards buffer (it+1)&1
    if (it + 1 < 32) {
      const u16* kt = kptr + (size_t)(it + 1) * 4096;
      const int b1 = (it + 1) & 1;
      async16(kt + (size_t)s0 * 8, Ksf[b1] + lo0);
      async16(kt + (size_t)s1 * 8, Ksf[b1] + lo1);
    }
    const u16* Kt = Ksf[it & 1];

    // V fragments direct from global (coalesced; L1-resident; consumed
    // only after the S+softmax+P phase -> latency shadowed)
    const u16* vt = vptr + (size_t)it * 4096;
    short8 vf[4][2];
#pragma unroll
    for (int et = 0; et < 4; ++et)
#pragma unroll
      for (int hf = 0; hf < 2; ++hf)
        vf[et][hf] =
            *(const short8*)(vt + (et * 2 + hf) * 512 + lane * 8);

    // S^T = K . Q^T per 16-key tile; Schraudolph 2^s; b64-write P[q][key]
#pragma unroll
    for (int t = 0; t < 4; ++t) {
      const short8 kf0 = *(const short8*)(Kt + t * 1024 + lane * 8);
      const short8 kf1 = *(const short8*)(Kt + t * 1024 + 512 + lane * 8);
#pragma unroll
      for (int sub = 0; sub < 2; ++sub) {
        floatx4 z;
#pragma unroll
        for (int r = 0; r < 4; ++r) z[r] = 0.f;
        z = MFMA16(kf0, aq[sub][0], z);
        z = MFMA16(kf1, aq[sub][1], z);
        // D[key = t*16+quad*4+r][q = l16]
        uint2 w;
        w.x = p2b(z[0]) | (p2b(z[1]) << 16);
        w.y = p2b(z[2]) | (p2b(z[3]) << 16);
        *(uint2*)(Ps[wave][sub] + l16 * 72 + t * 16 + quad * 4) = w;
      }
    }

    // same-wave DS ordering: drain P writes before fragment reads
    __asm__ volatile("s_waitcnt lgkmcnt(0)" ::: "memory");

    short8 pa[2][2];
#pragma unroll
    for (int sub = 0; sub < 2; ++sub) {
      pa[sub][0] = *(const short8*)(Ps[wave][sub] + l16 * 72 + quad * 8);
      pa[sub][1] = *(const short8*)(Ps[wave][sub] + l16 * 72 + 32 + quad * 8);
    }

    // O += P . V ; l += P . 1
#pragma unroll
    for (int et = 0; et < 4; ++et)
#pragma unroll
      for (int sub = 0; sub < 2; ++sub) {
        o[sub][et] = MFMA16(pa[sub][0], vf[et][0], o[sub][et]);
        o[sub][et] = MFMA16(pa[sub][1], vf[et][1], o[sub][et]);
      }
#pragma unroll
    for (int sub = 0; sub < 2; ++sub) {
      ol[sub] = MFMA16(pa[sub][0], ones, ol[sub]);
      ol[sub] = MFMA16(pa[sub][1], ones, ol[sub]);
    }
  }

  // epilogue: O / l -> ob[b][n][h*64+e] (bf16)
  const int b = bh >> 4, h = bh & 15;
#pragma unroll
  for (int sub = 0; sub < 2; ++sub) {
    float inv[4];
#pragma unroll
    for (int r = 0; r < 4; ++r) inv[r] = 1.0f / ol[sub][r];
#pragma unroll
    for (int et = 0; et < 4; ++et)
#pragma unroll
      for (int r = 0; r < 4; ++r) {
        const int row = q0 + wave * 32 + sub * 16 + quad * 4 + r;
        const int e = et * 16 + l16;
        ob[((size_t)b * 2048 + row) * 1024 + h * 64 + e] =
            f2bf(o[sub][et][r] * inv[r]);
      }
  }
}

extern "C" void kernel_launch(void* const* d_in, const int* in_sizes, int n_in,
                              void* d_out, int out_size, void* d_ws, size_t ws_size,
                              hipStream_t stream) {
  const float* x     = (const float*)d_in[0];
  const float* cosp  = (const float*)d_in[1];
  const float* sinp  = (const float*)d_in[2];
  const float* wqkv  = (const float*)d_in[3];
  const float* wproj = (const float*)d_in[4];
  const float* bias  = (const float*)d_in[5];
  const float* qw    = (const float*)d_in[6];
  const float* kw    = (const float*)d_in[7];
  float* out = (float*)d_out;

  // workspace layout (u16), total ~88 MB
  u16* xb     = (u16*)d_ws;
  u16* wqkvb  = xb + SZ_X;
  u16* wprojb = wqkvb + SZ_WQKV;
  u16* qb     = wprojb + SZ_WPROJ;
  u16* kb     = qb + SZ_QKV;
  u16* vtb    = kb + SZ_QKV;
  u16* ob     = vtb + SZ_QKV;

  const int ncvt = (int)((SZ_X + SZ_WQKV + SZ_WPROJ) / 4 / 256);
  cvt_all<<<ncvt, 256, 0, stream>>>(x, wqkv, wproj, xb, wqkvb, wprojb);

  gemm_bt<0><<<dim3(64, 24), 256, 0, stream>>>(xb, wqkvb, 1024, qb, kb, vtb,
                                               nullptr, nullptr, 3072,
                                               cosp, sinp, qw, kw);
  attn_kernel<<<dim3(16, 64), 256, 0, stream>>>(qb, kb, vtb, ob);
  gemm_bt<1><<<dim3(64, 8), 256, 0, stream>>>(ob, wprojb, 1024, nullptr, nullptr,
                                              nullptr, out, bias, 1024,
                                              nullptr, nullptr, nullptr, nullptr);
}